// Round 1
// 541.888 us; speedup vs baseline: 1.0396x; 1.0396x over previous
//
#include <hip/hip_runtime.h>
#include <cmath>
#include <cstdint>

// Problem constants: B=32, S=2048, E=1024, D=1024
constexpr int B_ = 32;
constexpr int S_ = 2048;
constexpr int E_ = 1024;
constexpr int D_ = 1024;
constexpr int K_ = E_;        // GEMM K
constexpr int M_ = S_ * B_;   // 65536 rows (m = s*B + b)
constexpr int SC_ = 32;       // context s-chunks
constexpr int NP_ = 16;       // score partial planes (4 nb x 4 wn)

typedef float f32x4 __attribute__((ext_vector_type(4)));
typedef float fvec4 __attribute__((ext_vector_type(4)));
typedef __bf16 bf16x8 __attribute__((ext_vector_type(8)));
typedef __attribute__((address_space(3))) uint32_t lds_u32;
typedef const __attribute__((address_space(1))) uint32_t g_u32;

// fast tanh: 1 - 2/(exp(2x)+1); saturates correctly; ~6 VALU ops
__device__ __forceinline__ float fast_tanh(float x) {
    float e = __builtin_amdgcn_exp2f(x * 2.88539008177793f);
    return 1.f - 2.f * __builtin_amdgcn_rcpf(e + 1.f);
}

__device__ __forceinline__ uint16_t f2bf(float f) {
    uint32_t u = __float_as_uint(f);
    u += 0x7FFFu + ((u >> 16) & 1u);
    return (uint16_t)(u >> 16);
}

// ---------------------------------------------------------------------------
// K0: fused prep: fp32->bf16 convert (enc, We) + dec_proj.
// ---------------------------------------------------------------------------
constexpr int ENC_N8 = M_ * K_ / 8;   // 8388608
constexpr int WE_N8  = D_ * K_ / 8;   // 131072
constexpr int CVT_BLOCKS = (ENC_N8 + WE_N8) / 256;  // 33280
constexpr int DEC_BLOCKS = (B_ * D_) / 4;           // 8192

__global__ __launch_bounds__(256) void prep_kernel(
    const float* __restrict__ enc, uint16_t* __restrict__ encb,
    const float* __restrict__ We,  uint16_t* __restrict__ Web,
    const float* __restrict__ hidden, const float* __restrict__ Wd,
    float* __restrict__ dec)
{
    const int bid = blockIdx.x;
    if (bid < CVT_BLOCKS) {
        int tid = bid * 256 + threadIdx.x;
        const float* src;
        uint16_t* dst;
        int i8;
        if (tid < ENC_N8) { src = enc; dst = encb; i8 = tid; }
        else              { src = We;  dst = Web;  i8 = tid - ENC_N8; }
        const fvec4* s4 = reinterpret_cast<const fvec4*>(src) + (size_t)i8 * 2;
        fvec4 a = __builtin_nontemporal_load(s4);
        fvec4 b = __builtin_nontemporal_load(s4 + 1);
        uint4 o;
        o.x = (uint32_t)f2bf(a.x) | ((uint32_t)f2bf(a.y) << 16);
        o.y = (uint32_t)f2bf(a.z) | ((uint32_t)f2bf(a.w) << 16);
        o.z = (uint32_t)f2bf(b.x) | ((uint32_t)f2bf(b.y) << 16);
        o.w = (uint32_t)f2bf(b.z) | ((uint32_t)f2bf(b.w) << 16);
        reinterpret_cast<uint4*>(dst)[i8] = o;
    } else {
        const int o = (bid - CVT_BLOCKS) * 4 + (threadIdx.x >> 6);
        const int lane = threadIdx.x & 63;
        const int b = o >> 10;
        const int d = o & (D_ - 1);
        const float4* h4 = reinterpret_cast<const float4*>(hidden + (size_t)b * D_);
        const float4* w4 = reinterpret_cast<const float4*>(Wd + (size_t)d * D_);
        float acc = 0.f;
#pragma unroll
        for (int p = 0; p < 4; ++p) {
            float4 h = h4[lane + p * 64], w = w4[lane + p * 64];
            acc += h.x * w.x + h.y * w.y + h.z * w.z + h.w * w.w;
        }
#pragma unroll
        for (int off = 32; off > 0; off >>= 1) acc += __shfl_xor(acc, off);
        if (lane == 0) dec[o] = acc;
    }
}

// ---------------------------------------------------------------------------
// K2: MFMA bf16 GEMM fused with tanh + v-dot -> 16 partial score planes.
// 256x256 tile, BK=32, 8 waves (2M x 4N), 4-deep LDS ring (128 KiB),
// counted vmcnt(8) (3-tile prefetch, never drained to 0 in steady state),
// XOR-swizzled LDS (byte ^= (row&7)<<4) staged via pre-swizzled per-lane
// global_load_lds sources (offset imm kept 0 - not safe for global->LDS),
// setprio(1) around 16-MFMA clusters, raw s_barrier (no waitcnt-0 barrier).
// ---------------------------------------------------------------------------
constexpr int TM2 = 256, TN2 = 256, TK2 = 32;
constexpr int NT2 = K_ / TK2;            // 32 K-tiles
constexpr int TILE_B = TM2 * TK2 * 2;    // 16384 B per matrix tile
constexpr int BUF_B  = TILE_B * 2;       // 32768 B per ring slot (A+B)

#define TILE_STEP(T, DO_STAGE)                                                \
  do {                                                                        \
    const int buf_ = (T) & 3;                                                 \
    const char* bufA_ = ldsc + buf_ * BUF_B;                                  \
    const char* bufB_ = bufA_ + TILE_B;                                       \
    bf16x8 a0_[4], bv_[4];                                                    \
    _Pragma("unroll")                                                         \
    for (int i = 0; i < 4; ++i)                                               \
      a0_[i] = __builtin_bit_cast(bf16x8,                                     \
          *reinterpret_cast<const int4*>(bufA_ + offA[i]));                   \
    _Pragma("unroll")                                                         \
    for (int j = 0; j < 4; ++j)                                               \
      bv_[j] = __builtin_bit_cast(bf16x8,                                     \
          *reinterpret_cast<const int4*>(bufB_ + offB[j]));                   \
    if (DO_STAGE) {                                                           \
      char* sb_ = ldsc + (((T) + 3) & 3) * BUF_B;                             \
      __builtin_amdgcn_global_load_lds((g_u32*)pA0, (lds_u32*)(sb_ + dst0), 16, 0, 0); \
      __builtin_amdgcn_global_load_lds((g_u32*)pA1, (lds_u32*)(sb_ + dst1), 16, 0, 0); \
      pA0 += TK2; pA1 += TK2;                                                 \
    }                                                                         \
    __builtin_amdgcn_s_barrier();                                             \
    asm volatile("s_waitcnt lgkmcnt(0)" ::: "memory");                        \
    __builtin_amdgcn_sched_barrier(0);                                        \
    __builtin_amdgcn_s_setprio(1);                                            \
    _Pragma("unroll")                                                         \
    for (int i = 0; i < 4; ++i)                                               \
      _Pragma("unroll")                                                       \
      for (int j = 0; j < 4; ++j)                                             \
        acc[i][j] = __builtin_amdgcn_mfma_f32_16x16x32_bf16(                  \
            a0_[i], bv_[j], acc[i][j], 0, 0, 0);                              \
    __builtin_amdgcn_s_setprio(0);                                            \
    __builtin_amdgcn_s_barrier();                                             \
    bf16x8 a1_[4];                                                            \
    _Pragma("unroll")                                                         \
    for (int i = 0; i < 4; ++i)                                               \
      a1_[i] = __builtin_bit_cast(bf16x8,                                     \
          *reinterpret_cast<const int4*>(bufA_ + offA[4 + i]));               \
    if (DO_STAGE) {                                                           \
      char* sb_ = ldsc + (((T) + 3) & 3) * BUF_B + TILE_B;                    \
      __builtin_amdgcn_global_load_lds((g_u32*)pB0, (lds_u32*)(sb_ + dst0), 16, 0, 0); \
      __builtin_amdgcn_global_load_lds((g_u32*)pB1, (lds_u32*)(sb_ + dst1), 16, 0, 0); \
      pB0 += TK2; pB1 += TK2;                                                 \
    }                                                                         \
    __builtin_amdgcn_s_barrier();                                             \
    asm volatile("s_waitcnt lgkmcnt(0)" ::: "memory");                        \
    __builtin_amdgcn_sched_barrier(0);                                        \
    __builtin_amdgcn_s_setprio(1);                                            \
    _Pragma("unroll")                                                         \
    for (int i = 0; i < 4; ++i)                                               \
      _Pragma("unroll")                                                       \
      for (int j = 0; j < 4; ++j)                                             \
        acc[4 + i][j] = __builtin_amdgcn_mfma_f32_16x16x32_bf16(              \
            a1_[i], bv_[j], acc[4 + i][j], 0, 0, 0);                          \
    __builtin_amdgcn_s_setprio(0);                                            \
  } while (0)

__global__ __launch_bounds__(512, 2) void score_mfma_kernel(
    const uint16_t* __restrict__ A,   // enc bf16 [M, K]
    const uint16_t* __restrict__ Bw,  // We  bf16 [D, K]
    const float* __restrict__ dec,    // [B, D]
    const float* __restrict__ v,      // [D]
    float* __restrict__ spart)        // [NP_, M_]  (rows are b*S + s)
{
    __shared__ __align__(16) uint16_t smem[4 * 2 * TM2 * TK2];  // 128 KiB

    // XCD-aware decode: the 4 n-blocks of one m-tile sit on one XCD
    const int p    = blockIdx.x;
    const int xcd  = p & 7;
    const int slot = p >> 3;
    const int nb   = slot & 3;
    const int mb   = xcd + 8 * (slot >> 2);
    const int m0 = mb * TM2;
    const int n0 = nb * TN2;

    const int tid  = threadIdx.x;
    const int wave = tid >> 6;        // 0..7
    const int lane = tid & 63;
    const int wm   = wave >> 2;       // 0..1 : 128 output rows each
    const int wn   = wave & 3;        // 0..3 : 64 output cols each
    const int q    = lane >> 4;
    const int r16  = lane & 15;

    char* ldsc = (char*)smem;

    // ds_read byte offsets within one 16 KiB matrix tile (swizzled).
    // element (row,k) stored at (row*64 + k*2) ^ ((row&7)<<4)
    int offA[8], offB[4];
#pragma unroll
    for (int i = 0; i < 8; ++i) {
        const int r = wm * 128 + i * 16 + r16;
        offA[i] = (r * 64 + q * 16) ^ ((r & 7) << 4);
    }
#pragma unroll
    for (int j = 0; j < 4; ++j) {
        const int r = wn * 64 + j * 16 + r16;
        offB[j] = (r * 64 + q * 16) ^ ((r & 7) << 4);
    }

    // staging sources: global_load_lds writes LDS linearly (base+lane*16),
    // so the swizzle is applied by permuting the per-lane GLOBAL source.
    // stored row rS = chunk + (lane>>2); logical row = rS ^ ((rS>>2)&1);
    // logical k-granule = (lane&3) ^ (rowL&3).
    const int l2     = lane >> 2;
    const int bbit   = (lane >> 4) & 1;
    const int rowSwz = l2 ^ bbit;                   // 0..15
    const int gsel   = (lane & 3) ^ (rowSwz & 3);   // 0..3
    const uint16_t* pA0 = A  + (size_t)(m0 + wave * 32 +  0 + rowSwz) * K_ + gsel * 8;
    const uint16_t* pA1 = A  + (size_t)(m0 + wave * 32 + 16 + rowSwz) * K_ + gsel * 8;
    const uint16_t* pB0 = Bw + (size_t)(n0 + wave * 32 +  0 + rowSwz) * K_ + gsel * 8;
    const uint16_t* pB1 = Bw + (size_t)(n0 + wave * 32 + 16 + rowSwz) * K_ + gsel * 8;
    const int dst0 = wave * 2048;      // this wave's first 1 KiB within a tile
    const int dst1 = dst0 + 1024;

    // prologue: stage tiles 0,1,2 (ring slots 0,1,2); FIFO [t0 x4][t1 x4][t2 x4]
#pragma unroll
    for (int tt = 0; tt < 3; ++tt) {
        char* sb = ldsc + tt * BUF_B;
        __builtin_amdgcn_global_load_lds((g_u32*)pA0, (lds_u32*)(sb + dst0), 16, 0, 0);
        __builtin_amdgcn_global_load_lds((g_u32*)pA1, (lds_u32*)(sb + dst1), 16, 0, 0);
        __builtin_amdgcn_global_load_lds((g_u32*)pB0, (lds_u32*)(sb + TILE_B + dst0), 16, 0, 0);
        __builtin_amdgcn_global_load_lds((g_u32*)pB1, (lds_u32*)(sb + TILE_B + dst1), 16, 0, 0);
        pA0 += TK2; pA1 += TK2; pB0 += TK2; pB1 += TK2;
    }
    asm volatile("s_waitcnt vmcnt(8)" ::: "memory");  // tile 0 landed
    __builtin_amdgcn_s_barrier();

    f32x4 acc[8][4] = {};

    // main loop: per-wave FIFO at tile end = [t+1:4][t+2:4][t+3:4];
    // vmcnt(8) retires exactly tile t+1's 4 loads before its first ds_read.
#pragma unroll 1
    for (int t = 0; t < NT2 - 3; ++t) {   // t = 0..28
        TILE_STEP(t, true);
        asm volatile("s_waitcnt vmcnt(8)" ::: "memory");
        __builtin_amdgcn_s_barrier();
    }
    TILE_STEP(NT2 - 3, false);            // t = 29
    asm volatile("s_waitcnt vmcnt(4)" ::: "memory");
    __builtin_amdgcn_s_barrier();
    TILE_STEP(NT2 - 2, false);            // t = 30
    asm volatile("s_waitcnt vmcnt(0)" ::: "memory");
    __builtin_amdgcn_s_barrier();
    TILE_STEP(NT2 - 1, false);            // t = 31

    // epilogue: C/D layout col = lane&15, row = q*4 + reg.
    // dec/v loaded here (not preloaded) to keep main-loop VGPRs down.
    float vj[4];
#pragma unroll
    for (int j = 0; j < 4; ++j) vj[j] = v[n0 + wn * 64 + j * 16 + r16];
    float dec_r[2][4][4];   // [i&1][r][j]; b = (i&1)*16 + q*4 + r
#pragma unroll
    for (int i01 = 0; i01 < 2; ++i01)
#pragma unroll
        for (int r = 0; r < 4; ++r) {
            const int b = i01 * 16 + q * 4 + r;
#pragma unroll
            for (int j = 0; j < 4; ++j)
                dec_r[i01][r][j] = dec[b * D_ + n0 + wn * 64 + j * 16 + r16];
        }

    float* plane = spart + (size_t)(nb * 4 + wn) * M_;

#pragma unroll
    for (int i = 0; i < 8; ++i) {
#pragma unroll
        for (int r = 0; r < 4; ++r) {
            const int m = m0 + wm * 128 + i * 16 + q * 4 + r;
            const int b = (i & 1) * 16 + q * 4 + r;
            float pv = 0.f;
#pragma unroll
            for (int j = 0; j < 4; ++j)
                pv += vj[j] * fast_tanh(acc[i][j][r] + dec_r[i & 1][r][j]);
            pv += __shfl_xor(pv, 1);
            pv += __shfl_xor(pv, 2);
            pv += __shfl_xor(pv, 4);
            pv += __shfl_xor(pv, 8);
            if (r16 == 0) plane[b * S_ + (m >> 5)] = pv;
        }
    }
}

// ---------------------------------------------------------------------------
// K3: softmax over s per batch; sums the 16 partial planes first.
// ---------------------------------------------------------------------------
__global__ __launch_bounds__(256) void softmax16_kernel(
    const float* __restrict__ spart,  // [NP_, M_], plane rows are [b][s]
    float* __restrict__ attn)         // [B, S]
{
    const int b = blockIdx.x;
    const int t = threadIdx.x;
    __shared__ float sm[256];

    const float4* base = reinterpret_cast<const float4*>(spart + (size_t)b * S_);
    constexpr int PSTRIDE = M_ / 4;
    float4 v0 = {0, 0, 0, 0}, v1 = {0, 0, 0, 0};
#pragma unroll
    for (int p = 0; p < NP_; ++p) {
        float4 a = base[(size_t)p * PSTRIDE + t];
        float4 c = base[(size_t)p * PSTRIDE + t + 256];
        v0.x += a.x; v0.y += a.y; v0.z += a.z; v0.w += a.w;
        v1.x += c.x; v1.y += c.y; v1.z += c.z; v1.w += c.w;
    }

    float lmax = fmaxf(fmaxf(fmaxf(v0.x, v0.y), fmaxf(v0.z, v0.w)),
                       fmaxf(fmaxf(v1.x, v1.y), fmaxf(v1.z, v1.w)));
    sm[t] = lmax; __syncthreads();
    for (int off = 128; off > 0; off >>= 1) {
        if (t < off) sm[t] = fmaxf(sm[t], sm[t + off]);
        __syncthreads();
    }
    const float mx = sm[0];
    __syncthreads();

    v0.x = __builtin_amdgcn_exp2f((v0.x - mx) * 1.44269504f);
    v0.y = __builtin_amdgcn_exp2f((v0.y - mx) * 1.44269504f);
    v0.z = __builtin_amdgcn_exp2f((v0.z - mx) * 1.44269504f);
    v0.w = __builtin_amdgcn_exp2f((v0.w - mx) * 1.44269504f);
    v1.x = __builtin_amdgcn_exp2f((v1.x - mx) * 1.44269504f);
    v1.y = __builtin_amdgcn_exp2f((v1.y - mx) * 1.44269504f);
    v1.z = __builtin_amdgcn_exp2f((v1.z - mx) * 1.44269504f);
    v1.w = __builtin_amdgcn_exp2f((v1.w - mx) * 1.44269504f);

    float lsum = v0.x + v0.y + v0.z + v0.w + v1.x + v1.y + v1.z + v1.w;
    sm[t] = lsum; __syncthreads();
    for (int off = 128; off > 0; off >>= 1) {
        if (t < off) sm[t] += sm[t + off];
        __syncthreads();
    }
    const float inv = 1.f / sm[0];
    float4* op = reinterpret_cast<float4*>(attn + (size_t)b * S_);
    v0.x *= inv; v0.y *= inv; v0.z *= inv; v0.w *= inv;
    v1.x *= inv; v1.y *= inv; v1.z *= inv; v1.w *= inv;
    op[t] = v0; op[t + 256] = v1;
}

// ---------------------------------------------------------------------------
// K4a: context partials (reuses spart region); K4b: reduce.
// ---------------------------------------------------------------------------
__global__ __launch_bounds__(256) void context_part_kernel(
    const uint16_t* __restrict__ encb, const float* __restrict__ attn,
    float* __restrict__ part)          // [SC_, B, E]
{
    const int b  = blockIdx.x & (B_ - 1);
    const int sc = blockIdx.x >> 5;
    const int e0 = threadIdx.x * 4;
    constexpr int SLEN = S_ / SC_;     // 64

    float a0 = 0.f, a1 = 0.f, a2 = 0.f, a3 = 0.f;
    const int s0 = sc * SLEN;
#pragma unroll 2
    for (int s = s0; s < s0 + SLEN; ++s) {
        const float w = attn[b * S_ + s];
        uint2 u = *reinterpret_cast<const uint2*>(
            encb + ((size_t)s * B_ + b) * E_ + e0);
        a0 += w * __uint_as_float((u.x & 0xFFFFu) << 16);
        a1 += w * __uint_as_float(u.x & 0xFFFF0000u);
        a2 += w * __uint_as_float((u.y & 0xFFFFu) << 16);
        a3 += w * __uint_as_float(u.y & 0xFFFF0000u);
    }
    float4 o = {a0, a1, a2, a3};
    *reinterpret_cast<float4*>(part + ((size_t)sc * B_ + b) * E_ + e0) = o;
}

__global__ __launch_bounds__(256) void context_reduce_kernel(
    const float* __restrict__ part, float* __restrict__ ctx)
{
    const int i = blockIdx.x * 256 + threadIdx.x;
    float acc = 0.f;
#pragma unroll
    for (int sc = 0; sc < SC_; ++sc) acc += part[(size_t)sc * B_ * E_ + i];
    ctx[i] = acc;
}

// ---------------------------------------------------------------------------
// Fallback fp32 path (ws too small)
// ---------------------------------------------------------------------------
constexpr int BM = 64, BN = 64, BK = 16;

__global__ __launch_bounds__(256) void dec_proj_wave_kernel(
    const float* __restrict__ hidden, const float* __restrict__ Wd,
    float* __restrict__ dec)
{
    const int o = blockIdx.x * 4 + (threadIdx.x >> 6);
    const int lane = threadIdx.x & 63;
    const int b = o >> 10;
    const int d = o & (D_ - 1);
    const float4* h4 = reinterpret_cast<const float4*>(hidden + (size_t)b * D_);
    const float4* w4 = reinterpret_cast<const float4*>(Wd + (size_t)d * D_);
    float acc = 0.f;
#pragma unroll
    for (int p = 0; p < 4; ++p) {
        float4 h = h4[lane + p * 64], w = w4[lane + p * 64];
        acc += h.x * w.x + h.y * w.y + h.z * w.z + h.w * w.w;
    }
#pragma unroll
    for (int off = 32; off > 0; off >>= 1) acc += __shfl_xor(acc, off);
    if (lane == 0) dec[o] = acc;
}

__global__ __launch_bounds__(256) void score_gemm_kernel(
    const float* __restrict__ enc, const float* __restrict__ We,
    const float* __restrict__ dec, const float* __restrict__ v,
    float* __restrict__ scores)
{
    __shared__ float As[BM][BK + 1];
    __shared__ float Bs[BN][BK + 1];
    __shared__ float red[BM][17];
    const int m0 = blockIdx.x * BM;
    const int n0 = blockIdx.y * BN;
    const int t  = threadIdx.x;
    const int tx = t & 15;
    const int ty = t >> 4;
    const int lrow = t >> 2;
    const int lcol = (t & 3) * 4;
    float acc[4][4] = {};
    for (int k0 = 0; k0 < E_; k0 += BK) {
        float4 a = *reinterpret_cast<const float4*>(enc + (size_t)(m0 + lrow) * E_ + k0 + lcol);
        float4 w = *reinterpret_cast<const float4*>(We + (size_t)(n0 + lrow) * E_ + k0 + lcol);
        As[lrow][lcol + 0] = a.x; As[lrow][lcol + 1] = a.y;
        As[lrow][lcol + 2] = a.z; As[lrow][lcol + 3] = a.w;
        Bs[lrow][lcol + 0] = w.x; Bs[lrow][lcol + 1] = w.y;
        Bs[lrow][lcol + 2] = w.z; Bs[lrow][lcol + 3] = w.w;
        __syncthreads();
#pragma unroll
        for (int kk = 0; kk < BK; ++kk) {
            float av[4], bw[4];
#pragma unroll
            for (int i = 0; i < 4; ++i) av[i] = As[ty * 4 + i][kk];
#pragma unroll
            for (int j = 0; j < 4; ++j) bw[j] = Bs[tx * 4 + j][kk];
#pragma unroll
            for (int i = 0; i < 4; ++i)
#pragma unroll
                for (int j = 0; j < 4; ++j)
                    acc[i][j] += av[i] * bw[j];
        }
        __syncthreads();
    }
    float pp[4];
#pragma unroll
    for (int i = 0; i < 4; ++i) {
        int m = m0 + ty * 4 + i;
        int b = m & (B_ - 1);
        float s = 0.f;
#pragma unroll
        for (int j = 0; j < 4; ++j) {
            int n = n0 + tx * 4 + j;
            s += v[n] * tanhf(acc[i][j] + dec[b * D_ + n]);
        }
        pp[i] = s;
    }
#pragma unroll
    for (int i = 0; i < 4; ++i) red[ty * 4 + i][tx] = pp[i];
    __syncthreads();
    if (t < BM) {
        float s = 0.f;
#pragma unroll
        for (int j = 0; j < 16; ++j) s += red[t][j];
        atomicAdd(&scores[m0 + t], s);
    }
}

__global__ __launch_bounds__(256) void softmax_kernel(
    const float* __restrict__ scores, float* __restrict__ attn)
{
    const int b = blockIdx.x;
    const int t = threadIdx.x;
    __shared__ float sm[256];
    float vals[8];
    float lmax = -INFINITY;
#pragma unroll
    for (int i = 0; i < 8; ++i) {
        int s = t + i * 256;
        vals[i] = scores[s * B_ + b];
        lmax = fmaxf(lmax, vals[i]);
    }
    sm[t] = lmax; __syncthreads();
    for (int off = 128; off > 0; off >>= 1) {
        if (t < off) sm[t] = fmaxf(sm[t], sm[t + off]);
        __syncthreads();
    }
    const float mx = sm[0];
    __syncthreads();
    float lsum = 0.f;
#pragma unroll
    for (int i = 0; i < 8; ++i) {
        vals[i] = expf(vals[i] - mx);
        lsum += vals[i];
    }
    sm[t] = lsum; __syncthreads();
    for (int off = 128; off > 0; off >>= 1) {
        if (t < off) sm[t] += sm[t + off];
        __syncthreads();
    }
    const float inv = 1.f / sm[0];
#pragma unroll
    for (int i = 0; i < 8; ++i)
        attn[b * S_ + t + i * 256] = vals[i] * inv;
}

__global__ __launch_bounds__(256) void context_kernel(
    const float* __restrict__ enc, const float* __restrict__ attn,
    float* __restrict__ ctx)
{
    const int e0 = (blockIdx.x & 3) * 256;
    const int b  = (blockIdx.x >> 2) & (B_ - 1);
    const int sc = blockIdx.x >> 7;
    const int e  = e0 + threadIdx.x;
    float acc = 0.f;
    const int s_end = sc * 256 + 256;
    for (int s = sc * 256; s < s_end; ++s)
        acc += attn[b * S_ + s] * enc[((size_t)s * B_ + b) * E_ + e];
    atomicAdd(&ctx[b * E_ + e], acc);
}

// ---------------------------------------------------------------------------
extern "C" void kernel_launch(void* const* d_in, const int* in_sizes, int n_in,
                              void* d_out, int out_size, void* d_ws, size_t ws_size,
                              hipStream_t stream) {
    const float* hidden = (const float*)d_in[0];
    const float* enc    = (const float*)d_in[1];
    const float* We     = (const float*)d_in[2];
    const float* Wd     = (const float*)d_in[3];
    const float* v      = (const float*)d_in[4];

    float* ctx  = (float*)d_out;
    float* attn = (float*)d_out + B_ * E_;

    float*    dec   = (float*)d_ws;                  // [B*D]
    float*    spart = dec + B_ * D_;                 // [NP_*M_] (reused as ctx partials)
    uint16_t* Web   = (uint16_t*)(spart + (size_t)NP_ * M_);  // [D*K]
    uint16_t* encb  = Web + (size_t)D_ * K_;         // [M*K]

    const size_t need = (size_t)B_ * D_ * 4 + (size_t)NP_ * M_ * 4
                      + ((size_t)D_ * K_ + (size_t)M_ * K_) * 2;
    const bool fast = ws_size >= need;

    if (fast) {
        prep_kernel<<<CVT_BLOCKS + DEC_BLOCKS, 256, 0, stream>>>(
            enc, encb, We, Web, hidden, Wd, dec);

        score_mfma_kernel<<<(M_ / TM2) * (D_ / TN2), 512, 0, stream>>>(
            encb, Web, dec, v, spart);

        softmax16_kernel<<<B_, 256, 0, stream>>>(spart, attn);
        context_part_kernel<<<SC_ * B_, 256, 0, stream>>>(encb, attn, spart);
        context_reduce_kernel<<<(B_ * E_) / 256, 256, 0, stream>>>(spart, ctx);
    } else {
        float* scores = spart;
        hipMemsetAsync(scores, 0, (size_t)M_ * sizeof(float), stream);
        hipMemsetAsync(ctx, 0, (size_t)B_ * E_ * sizeof(float), stream);
        dec_proj_wave_kernel<<<(B_ * D_) / 4, 256, 0, stream>>>(hidden, Wd, dec);
        dim3 g2(M_ / BM, D_ / BN);
        score_gemm_kernel<<<g2, 256, 0, stream>>>(enc, We, dec, v, scores);
        softmax_kernel<<<B_, 256, 0, stream>>>(scores, attn);
        context_kernel<<<B_ * 4 * 8, 256, 0, stream>>>(enc, attn, ctx);
    }
}

// Round 2
// 538.924 us; speedup vs baseline: 1.0453x; 1.0055x over previous
//
#include <hip/hip_runtime.h>
#include <cmath>
#include <cstdint>

// Problem constants: B=32, S=2048, E=1024, D=1024
constexpr int B_ = 32;
constexpr int S_ = 2048;
constexpr int E_ = 1024;
constexpr int D_ = 1024;
constexpr int K_ = E_;        // GEMM K
constexpr int M_ = S_ * B_;   // 65536 rows (m = s*B + b)
constexpr int SC_ = 32;       // context s-chunks
constexpr int NP_ = 16;       // score partial planes (4 nb x 4 wn)

typedef float f32x4 __attribute__((ext_vector_type(4)));
typedef float fvec4 __attribute__((ext_vector_type(4)));
typedef __bf16 bf16x8 __attribute__((ext_vector_type(8)));
typedef __attribute__((address_space(3))) uint32_t lds_u32;
typedef const __attribute__((address_space(1))) uint32_t g_u32;

// fast tanh: 1 - 2/(exp(2x)+1); saturates correctly; ~6 VALU ops
__device__ __forceinline__ float fast_tanh(float x) {
    float e = __builtin_amdgcn_exp2f(x * 2.88539008177793f);
    return 1.f - 2.f * __builtin_amdgcn_rcpf(e + 1.f);
}

__device__ __forceinline__ uint16_t f2bf(float f) {
    uint32_t u = __float_as_uint(f);
    u += 0x7FFFu + ((u >> 16) & 1u);
    return (uint16_t)(u >> 16);
}

// ---------------------------------------------------------------------------
// K0: fused prep: fp32->bf16 convert (enc, We) + dec_proj.
// ---------------------------------------------------------------------------
constexpr int ENC_N8 = M_ * K_ / 8;   // 8388608
constexpr int WE_N8  = D_ * K_ / 8;   // 131072
constexpr int CVT_BLOCKS = (ENC_N8 + WE_N8) / 256;  // 33280
constexpr int DEC_BLOCKS = (B_ * D_) / 4;           // 8192

__global__ __launch_bounds__(256) void prep_kernel(
    const float* __restrict__ enc, uint16_t* __restrict__ encb,
    const float* __restrict__ We,  uint16_t* __restrict__ Web,
    const float* __restrict__ hidden, const float* __restrict__ Wd,
    float* __restrict__ dec)
{
    const int bid = blockIdx.x;
    if (bid < CVT_BLOCKS) {
        int tid = bid * 256 + threadIdx.x;
        const float* src;
        uint16_t* dst;
        int i8;
        if (tid < ENC_N8) { src = enc; dst = encb; i8 = tid; }
        else              { src = We;  dst = Web;  i8 = tid - ENC_N8; }
        const fvec4* s4 = reinterpret_cast<const fvec4*>(src) + (size_t)i8 * 2;
        fvec4 a = __builtin_nontemporal_load(s4);
        fvec4 b = __builtin_nontemporal_load(s4 + 1);
        uint4 o;
        o.x = (uint32_t)f2bf(a.x) | ((uint32_t)f2bf(a.y) << 16);
        o.y = (uint32_t)f2bf(a.z) | ((uint32_t)f2bf(a.w) << 16);
        o.z = (uint32_t)f2bf(b.x) | ((uint32_t)f2bf(b.y) << 16);
        o.w = (uint32_t)f2bf(b.z) | ((uint32_t)f2bf(b.w) << 16);
        reinterpret_cast<uint4*>(dst)[i8] = o;
    } else {
        const int o = (bid - CVT_BLOCKS) * 4 + (threadIdx.x >> 6);
        const int lane = threadIdx.x & 63;
        const int b = o >> 10;
        const int d = o & (D_ - 1);
        const float4* h4 = reinterpret_cast<const float4*>(hidden + (size_t)b * D_);
        const float4* w4 = reinterpret_cast<const float4*>(Wd + (size_t)d * D_);
        float acc = 0.f;
#pragma unroll
        for (int p = 0; p < 4; ++p) {
            float4 h = h4[lane + p * 64], w = w4[lane + p * 64];
            acc += h.x * w.x + h.y * w.y + h.z * w.z + h.w * w.w;
        }
#pragma unroll
        for (int off = 32; off > 0; off >>= 1) acc += __shfl_xor(acc, off);
        if (lane == 0) dec[o] = acc;
    }
}

// ---------------------------------------------------------------------------
// K2: MFMA bf16 GEMM fused with tanh + v-dot -> 16 partial score planes.
// 256x256 tile, BK=32, 8 waves (2M x 4N), 4-deep LDS ring (128 KiB),
// counted vmcnt(8) (3-tile prefetch), XOR-swizzled LDS staged via
// pre-swizzled per-lane global_load_lds sources, setprio around MFMA.
// ROUND 2 CHANGE: ONE barrier per K-tile (was 4). Mid-tile barriers were
// not needed for correctness (all slot-t data is published at the tile-end
// vmcnt(8)+barrier of t-1; each wave's reads of slot t-1 are lgkm(0)-drained
// before it can reach that barrier, so staging into slot (t+3)&3 == (t-1)&3
// is race-free). Removing them lets waves desynchronize within a tile so
// LDS read service overlaps MFMA pipe drain via wave skew.
// ---------------------------------------------------------------------------
constexpr int TM2 = 256, TN2 = 256, TK2 = 32;
constexpr int NT2 = K_ / TK2;            // 32 K-tiles
constexpr int TILE_B = TM2 * TK2 * 2;    // 16384 B per matrix tile
constexpr int BUF_B  = TILE_B * 2;       // 32768 B per ring slot (A+B)

#define TILE_STEP(T, DO_STAGE)                                                \
  do {                                                                        \
    const int buf_ = (T) & 3;                                                 \
    const char* bufA_ = ldsc + buf_ * BUF_B;                                  \
    const char* bufB_ = bufA_ + TILE_B;                                       \
    bf16x8 a0_[4], bv_[4];                                                    \
    _Pragma("unroll")                                                         \
    for (int i = 0; i < 4; ++i)                                               \
      a0_[i] = __builtin_bit_cast(bf16x8,                                     \
          *reinterpret_cast<const int4*>(bufA_ + offA[i]));                   \
    _Pragma("unroll")                                                         \
    for (int j = 0; j < 4; ++j)                                               \
      bv_[j] = __builtin_bit_cast(bf16x8,                                     \
          *reinterpret_cast<const int4*>(bufB_ + offB[j]));                   \
    if (DO_STAGE) {                                                           \
      char* sb_ = ldsc + (((T) + 3) & 3) * BUF_B;                             \
      __builtin_amdgcn_global_load_lds((g_u32*)pA0, (lds_u32*)(sb_ + dst0), 16, 0, 0); \
      __builtin_amdgcn_global_load_lds((g_u32*)pA1, (lds_u32*)(sb_ + dst1), 16, 0, 0); \
      pA0 += TK2; pA1 += TK2;                                                 \
    }                                                                         \
    asm volatile("s_waitcnt lgkmcnt(0)" ::: "memory");                        \
    __builtin_amdgcn_sched_barrier(0);                                        \
    __builtin_amdgcn_s_setprio(1);                                            \
    _Pragma("unroll")                                                         \
    for (int i = 0; i < 4; ++i)                                               \
      _Pragma("unroll")                                                       \
      for (int j = 0; j < 4; ++j)                                             \
        acc[i][j] = __builtin_amdgcn_mfma_f32_16x16x32_bf16(                  \
            a0_[i], bv_[j], acc[i][j], 0, 0, 0);                              \
    __builtin_amdgcn_s_setprio(0);                                            \
    bf16x8 a1_[4];                                                            \
    _Pragma("unroll")                                                         \
    for (int i = 0; i < 4; ++i)                                               \
      a1_[i] = __builtin_bit_cast(bf16x8,                                     \
          *reinterpret_cast<const int4*>(bufA_ + offA[4 + i]));               \
    if (DO_STAGE) {                                                           \
      char* sb_ = ldsc + (((T) + 3) & 3) * BUF_B + TILE_B;                    \
      __builtin_amdgcn_global_load_lds((g_u32*)pB0, (lds_u32*)(sb_ + dst0), 16, 0, 0); \
      __builtin_amdgcn_global_load_lds((g_u32*)pB1, (lds_u32*)(sb_ + dst1), 16, 0, 0); \
      pB0 += TK2; pB1 += TK2;                                                 \
    }                                                                         \
    asm volatile("s_waitcnt lgkmcnt(0)" ::: "memory");                        \
    __builtin_amdgcn_sched_barrier(0);                                        \
    __builtin_amdgcn_s_setprio(1);                                            \
    _Pragma("unroll")                                                         \
    for (int i = 0; i < 4; ++i)                                               \
      _Pragma("unroll")                                                       \
      for (int j = 0; j < 4; ++j)                                             \
        acc[4 + i][j] = __builtin_amdgcn_mfma_f32_16x16x32_bf16(              \
            a1_[i], bv_[j], acc[4 + i][j], 0, 0, 0);                          \
    __builtin_amdgcn_s_setprio(0);                                            \
  } while (0)

__global__ __launch_bounds__(512, 2) void score_mfma_kernel(
    const uint16_t* __restrict__ A,   // enc bf16 [M, K]
    const uint16_t* __restrict__ Bw,  // We  bf16 [D, K]
    const float* __restrict__ dec,    // [B, D]
    const float* __restrict__ v,      // [D]
    float* __restrict__ spart)        // [NP_, M_]  (rows are b*S + s)
{
    __shared__ __align__(16) uint16_t smem[4 * 2 * TM2 * TK2];  // 128 KiB

    // XCD-aware decode: the 4 n-blocks of one m-tile sit on one XCD
    const int p    = blockIdx.x;
    const int xcd  = p & 7;
    const int slot = p >> 3;
    const int nb   = slot & 3;
    const int mb   = xcd + 8 * (slot >> 2);
    const int m0 = mb * TM2;
    const int n0 = nb * TN2;

    const int tid  = threadIdx.x;
    const int wave = tid >> 6;        // 0..7
    const int lane = tid & 63;
    const int wm   = wave >> 2;       // 0..1 : 128 output rows each
    const int wn   = wave & 3;        // 0..3 : 64 output cols each
    const int q    = lane >> 4;
    const int r16  = lane & 15;

    char* ldsc = (char*)smem;

    // ds_read byte offsets within one 16 KiB matrix tile (swizzled).
    // element (row,k) stored at (row*64 + k*2) ^ ((row&7)<<4)
    int offA[8], offB[4];
#pragma unroll
    for (int i = 0; i < 8; ++i) {
        const int r = wm * 128 + i * 16 + r16;
        offA[i] = (r * 64 + q * 16) ^ ((r & 7) << 4);
    }
#pragma unroll
    for (int j = 0; j < 4; ++j) {
        const int r = wn * 64 + j * 16 + r16;
        offB[j] = (r * 64 + q * 16) ^ ((r & 7) << 4);
    }

    // staging sources: global_load_lds writes LDS linearly (base+lane*16),
    // so the swizzle is applied by permuting the per-lane GLOBAL source.
    // stored row rS = chunk + (lane>>2); logical row = rS ^ ((rS>>2)&1);
    // logical k-granule = (lane&3) ^ (rowL&3).
    const int l2     = lane >> 2;
    const int bbit   = (lane >> 4) & 1;
    const int rowSwz = l2 ^ bbit;                   // 0..15
    const int gsel   = (lane & 3) ^ (rowSwz & 3);   // 0..3
    const uint16_t* pA0 = A  + (size_t)(m0 + wave * 32 +  0 + rowSwz) * K_ + gsel * 8;
    const uint16_t* pA1 = A  + (size_t)(m0 + wave * 32 + 16 + rowSwz) * K_ + gsel * 8;
    const uint16_t* pB0 = Bw + (size_t)(n0 + wave * 32 +  0 + rowSwz) * K_ + gsel * 8;
    const uint16_t* pB1 = Bw + (size_t)(n0 + wave * 32 + 16 + rowSwz) * K_ + gsel * 8;
    const int dst0 = wave * 2048;      // this wave's first 1 KiB within a tile
    const int dst1 = dst0 + 1024;

    // prologue: stage tiles 0,1,2 (ring slots 0,1,2); FIFO [t0 x4][t1 x4][t2 x4]
#pragma unroll
    for (int tt = 0; tt < 3; ++tt) {
        char* sb = ldsc + tt * BUF_B;
        __builtin_amdgcn_global_load_lds((g_u32*)pA0, (lds_u32*)(sb + dst0), 16, 0, 0);
        __builtin_amdgcn_global_load_lds((g_u32*)pA1, (lds_u32*)(sb + dst1), 16, 0, 0);
        __builtin_amdgcn_global_load_lds((g_u32*)pB0, (lds_u32*)(sb + TILE_B + dst0), 16, 0, 0);
        __builtin_amdgcn_global_load_lds((g_u32*)pB1, (lds_u32*)(sb + TILE_B + dst1), 16, 0, 0);
        pA0 += TK2; pA1 += TK2; pB0 += TK2; pB1 += TK2;
    }
    asm volatile("s_waitcnt vmcnt(8)" ::: "memory");  // tile 0 landed
    __builtin_amdgcn_s_barrier();

    f32x4 acc[8][4] = {};

    // main loop: ONE barrier per tile. Per-wave VMEM FIFO at tile end =
    // [t+1:4][t+2:4][t+3:4]; vmcnt(8) retires exactly tile t+1's 4 loads.
#pragma unroll 1
    for (int t = 0; t < NT2 - 3; ++t) {   // t = 0..28
        TILE_STEP(t, true);
        asm volatile("s_waitcnt vmcnt(8)" ::: "memory");
        __builtin_amdgcn_s_barrier();
    }
    TILE_STEP(NT2 - 3, false);            // t = 29
    asm volatile("s_waitcnt vmcnt(4)" ::: "memory");
    __builtin_amdgcn_s_barrier();
    TILE_STEP(NT2 - 2, false);            // t = 30
    asm volatile("s_waitcnt vmcnt(0)" ::: "memory");
    __builtin_amdgcn_s_barrier();
    TILE_STEP(NT2 - 1, false);            // t = 31

    // epilogue: C/D layout col = lane&15, row = q*4 + reg.
    // dec/v loaded here (not preloaded) to keep main-loop VGPRs down.
    float vj[4];
#pragma unroll
    for (int j = 0; j < 4; ++j) vj[j] = v[n0 + wn * 64 + j * 16 + r16];
    float dec_r[2][4][4];   // [i&1][r][j]; b = (i&1)*16 + q*4 + r
#pragma unroll
    for (int i01 = 0; i01 < 2; ++i01)
#pragma unroll
        for (int r = 0; r < 4; ++r) {
            const int b = i01 * 16 + q * 4 + r;
#pragma unroll
            for (int j = 0; j < 4; ++j)
                dec_r[i01][r][j] = dec[b * D_ + n0 + wn * 64 + j * 16 + r16];
        }

    float* plane = spart + (size_t)(nb * 4 + wn) * M_;

#pragma unroll
    for (int i = 0; i < 8; ++i) {
#pragma unroll
        for (int r = 0; r < 4; ++r) {
            const int m = m0 + wm * 128 + i * 16 + q * 4 + r;
            const int b = (i & 1) * 16 + q * 4 + r;
            float pv = 0.f;
#pragma unroll
            for (int j = 0; j < 4; ++j)
                pv += vj[j] * fast_tanh(acc[i][j][r] + dec_r[i & 1][r][j]);
            pv += __shfl_xor(pv, 1);
            pv += __shfl_xor(pv, 2);
            pv += __shfl_xor(pv, 4);
            pv += __shfl_xor(pv, 8);
            if (r16 == 0) plane[b * S_ + (m >> 5)] = pv;
        }
    }
}

// ---------------------------------------------------------------------------
// K3: softmax over s per batch; sums the 16 partial planes first.
// ---------------------------------------------------------------------------
__global__ __launch_bounds__(256) void softmax16_kernel(
    const float* __restrict__ spart,  // [NP_, M_], plane rows are [b][s]
    float* __restrict__ attn)         // [B, S]
{
    const int b = blockIdx.x;
    const int t = threadIdx.x;
    __shared__ float sm[256];

    const float4* base = reinterpret_cast<const float4*>(spart + (size_t)b * S_);
    constexpr int PSTRIDE = M_ / 4;
    float4 v0 = {0, 0, 0, 0}, v1 = {0, 0, 0, 0};
#pragma unroll
    for (int p = 0; p < NP_; ++p) {
        float4 a = base[(size_t)p * PSTRIDE + t];
        float4 c = base[(size_t)p * PSTRIDE + t + 256];
        v0.x += a.x; v0.y += a.y; v0.z += a.z; v0.w += a.w;
        v1.x += c.x; v1.y += c.y; v1.z += c.z; v1.w += c.w;
    }

    float lmax = fmaxf(fmaxf(fmaxf(v0.x, v0.y), fmaxf(v0.z, v0.w)),
                       fmaxf(fmaxf(v1.x, v1.y), fmaxf(v1.z, v1.w)));
    sm[t] = lmax; __syncthreads();
    for (int off = 128; off > 0; off >>= 1) {
        if (t < off) sm[t] = fmaxf(sm[t], sm[t + off]);
        __syncthreads();
    }
    const float mx = sm[0];
    __syncthreads();

    v0.x = __builtin_amdgcn_exp2f((v0.x - mx) * 1.44269504f);
    v0.y = __builtin_amdgcn_exp2f((v0.y - mx) * 1.44269504f);
    v0.z = __builtin_amdgcn_exp2f((v0.z - mx) * 1.44269504f);
    v0.w = __builtin_amdgcn_exp2f((v0.w - mx) * 1.44269504f);
    v1.x = __builtin_amdgcn_exp2f((v1.x - mx) * 1.44269504f);
    v1.y = __builtin_amdgcn_exp2f((v1.y - mx) * 1.44269504f);
    v1.z = __builtin_amdgcn_exp2f((v1.z - mx) * 1.44269504f);
    v1.w = __builtin_amdgcn_exp2f((v1.w - mx) * 1.44269504f);

    float lsum = v0.x + v0.y + v0.z + v0.w + v1.x + v1.y + v1.z + v1.w;
    sm[t] = lsum; __syncthreads();
    for (int off = 128; off > 0; off >>= 1) {
        if (t < off) sm[t] += sm[t + off];
        __syncthreads();
    }
    const float inv = 1.f / sm[0];
    float4* op = reinterpret_cast<float4*>(attn + (size_t)b * S_);
    v0.x *= inv; v0.y *= inv; v0.z *= inv; v0.w *= inv;
    v1.x *= inv; v1.y *= inv; v1.z *= inv; v1.w *= inv;
    op[t] = v0; op[t + 256] = v1;
}

// ---------------------------------------------------------------------------
// K4a: context partials (reuses spart region); K4b: reduce.
// ---------------------------------------------------------------------------
__global__ __launch_bounds__(256) void context_part_kernel(
    const uint16_t* __restrict__ encb, const float* __restrict__ attn,
    float* __restrict__ part)          // [SC_, B, E]
{
    const int b  = blockIdx.x & (B_ - 1);
    const int sc = blockIdx.x >> 5;
    const int e0 = threadIdx.x * 4;
    constexpr int SLEN = S_ / SC_;     // 64

    float a0 = 0.f, a1 = 0.f, a2 = 0.f, a3 = 0.f;
    const int s0 = sc * SLEN;
#pragma unroll 2
    for (int s = s0; s < s0 + SLEN; ++s) {
        const float w = attn[b * S_ + s];
        uint2 u = *reinterpret_cast<const uint2*>(
            encb + ((size_t)s * B_ + b) * E_ + e0);
        a0 += w * __uint_as_float((u.x & 0xFFFFu) << 16);
        a1 += w * __uint_as_float(u.x & 0xFFFF0000u);
        a2 += w * __uint_as_float((u.y & 0xFFFFu) << 16);
        a3 += w * __uint_as_float(u.y & 0xFFFF0000u);
    }
    float4 o = {a0, a1, a2, a3};
    *reinterpret_cast<float4*>(part + ((size_t)sc * B_ + b) * E_ + e0) = o;
}

__global__ __launch_bounds__(256) void context_reduce_kernel(
    const float* __restrict__ part, float* __restrict__ ctx)
{
    const int i = blockIdx.x * 256 + threadIdx.x;
    float acc = 0.f;
#pragma unroll
    for (int sc = 0; sc < SC_; ++sc) acc += part[(size_t)sc * B_ * E_ + i];
    ctx[i] = acc;
}

// ---------------------------------------------------------------------------
// Fallback fp32 path (ws too small)
// ---------------------------------------------------------------------------
constexpr int BM = 64, BN = 64, BK = 16;

__global__ __launch_bounds__(256) void dec_proj_wave_kernel(
    const float* __restrict__ hidden, const float* __restrict__ Wd,
    float* __restrict__ dec)
{
    const int o = blockIdx.x * 4 + (threadIdx.x >> 6);
    const int lane = threadIdx.x & 63;
    const int b = o >> 10;
    const int d = o & (D_ - 1);
    const float4* h4 = reinterpret_cast<const float4*>(hidden + (size_t)b * D_);
    const float4* w4 = reinterpret_cast<const float4*>(Wd + (size_t)d * D_);
    float acc = 0.f;
#pragma unroll
    for (int p = 0; p < 4; ++p) {
        float4 h = h4[lane + p * 64], w = w4[lane + p * 64];
        acc += h.x * w.x + h.y * w.y + h.z * w.z + h.w * w.w;
    }
#pragma unroll
    for (int off = 32; off > 0; off >>= 1) acc += __shfl_xor(acc, off);
    if (lane == 0) dec[o] = acc;
}

__global__ __launch_bounds__(256) void score_gemm_kernel(
    const float* __restrict__ enc, const float* __restrict__ We,
    const float* __restrict__ dec, const float* __restrict__ v,
    float* __restrict__ scores)
{
    __shared__ float As[BM][BK + 1];
    __shared__ float Bs[BN][BK + 1];
    __shared__ float red[BM][17];
    const int m0 = blockIdx.x * BM;
    const int n0 = blockIdx.y * BN;
    const int t  = threadIdx.x;
    const int tx = t & 15;
    const int ty = t >> 4;
    const int lrow = t >> 2;
    const int lcol = (t & 3) * 4;
    float acc[4][4] = {};
    for (int k0 = 0; k0 < E_; k0 += BK) {
        float4 a = *reinterpret_cast<const float4*>(enc + (size_t)(m0 + lrow) * E_ + k0 + lcol);
        float4 w = *reinterpret_cast<const float4*>(We + (size_t)(n0 + lrow) * E_ + k0 + lcol);
        As[lrow][lcol + 0] = a.x; As[lrow][lcol + 1] = a.y;
        As[lrow][lcol + 2] = a.z; As[lrow][lcol + 3] = a.w;
        Bs[lrow][lcol + 0] = w.x; Bs[lrow][lcol + 1] = w.y;
        Bs[lrow][lcol + 2] = w.z; Bs[lrow][lcol + 3] = w.w;
        __syncthreads();
#pragma unroll
        for (int kk = 0; kk < BK; ++kk) {
            float av[4], bw[4];
#pragma unroll
            for (int i = 0; i < 4; ++i) av[i] = As[ty * 4 + i][kk];
#pragma unroll
            for (int j = 0; j < 4; ++j) bw[j] = Bs[tx * 4 + j][kk];
#pragma unroll
            for (int i = 0; i < 4; ++i)
#pragma unroll
                for (int j = 0; j < 4; ++j)
                    acc[i][j] += av[i] * bw[j];
        }
        __syncthreads();
    }
    float pp[4];
#pragma unroll
    for (int i = 0; i < 4; ++i) {
        int m = m0 + ty * 4 + i;
        int b = m & (B_ - 1);
        float s = 0.f;
#pragma unroll
        for (int j = 0; j < 4; ++j) {
            int n = n0 + tx * 4 + j;
            s += v[n] * tanhf(acc[i][j] + dec[b * D_ + n]);
        }
        pp[i] = s;
    }
#pragma unroll
    for (int i = 0; i < 4; ++i) red[ty * 4 + i][tx] = pp[i];
    __syncthreads();
    if (t < BM) {
        float s = 0.f;
#pragma unroll
        for (int j = 0; j < 16; ++j) s += red[t][j];
        atomicAdd(&scores[m0 + t], s);
    }
}

__global__ __launch_bounds__(256) void softmax_kernel(
    const float* __restrict__ scores, float* __restrict__ attn)
{
    const int b = blockIdx.x;
    const int t = threadIdx.x;
    __shared__ float sm[256];
    float vals[8];
    float lmax = -INFINITY;
#pragma unroll
    for (int i = 0; i < 8; ++i) {
        int s = t + i * 256;
        vals[i] = scores[s * B_ + b];
        lmax = fmaxf(lmax, vals[i]);
    }
    sm[t] = lmax; __syncthreads();
    for (int off = 128; off > 0; off >>= 1) {
        if (t < off) sm[t] = fmaxf(sm[t], sm[t + off]);
        __syncthreads();
    }
    const float mx = sm[0];
    __syncthreads();
    float lsum = 0.f;
#pragma unroll
    for (int i = 0; i < 8; ++i) {
        vals[i] = expf(vals[i] - mx);
        lsum += vals[i];
    }
    sm[t] = lsum; __syncthreads();
    for (int off = 128; off > 0; off >>= 1) {
        if (t < off) sm[t] += sm[t + off];
        __syncthreads();
    }
    const float inv = 1.f / sm[0];
#pragma unroll
    for (int i = 0; i < 8; ++i)
        attn[b * S_ + t + i * 256] = vals[i] * inv;
}

__global__ __launch_bounds__(256) void context_kernel(
    const float* __restrict__ enc, const float* __restrict__ attn,
    float* __restrict__ ctx)
{
    const int e0 = (blockIdx.x & 3) * 256;
    const int b  = (blockIdx.x >> 2) & (B_ - 1);
    const int sc = blockIdx.x >> 7;
    const int e  = e0 + threadIdx.x;
    float acc = 0.f;
    const int s_end = sc * 256 + 256;
    for (int s = sc * 256; s < s_end; ++s)
        acc += attn[b * S_ + s] * enc[((size_t)s * B_ + b) * E_ + e];
    atomicAdd(&ctx[b * E_ + e], acc);
}

// ---------------------------------------------------------------------------
extern "C" void kernel_launch(void* const* d_in, const int* in_sizes, int n_in,
                              void* d_out, int out_size, void* d_ws, size_t ws_size,
                              hipStream_t stream) {
    const float* hidden = (const float*)d_in[0];
    const float* enc    = (const float*)d_in[1];
    const float* We     = (const float*)d_in[2];
    const float* Wd     = (const float*)d_in[3];
    const float* v      = (const float*)d_in[4];

    float* ctx  = (float*)d_out;
    float* attn = (float*)d_out + B_ * E_;

    float*    dec   = (float*)d_ws;                  // [B*D]
    float*    spart = dec + B_ * D_;                 // [NP_*M_] (reused as ctx partials)
    uint16_t* Web   = (uint16_t*)(spart + (size_t)NP_ * M_);  // [D*K]
    uint16_t* encb  = Web + (size_t)D_ * K_;         // [M*K]

    const size_t need = (size_t)B_ * D_ * 4 + (size_t)NP_ * M_ * 4
                      + ((size_t)D_ * K_ + (size_t)M_ * K_) * 2;
    const bool fast = ws_size >= need;

    if (fast) {
        prep_kernel<<<CVT_BLOCKS + DEC_BLOCKS, 256, 0, stream>>>(
            enc, encb, We, Web, hidden, Wd, dec);

        score_mfma_kernel<<<(M_ / TM2) * (D_ / TN2), 512, 0, stream>>>(
            encb, Web, dec, v, spart);

        softmax16_kernel<<<B_, 256, 0, stream>>>(spart, attn);
        context_part_kernel<<<SC_ * B_, 256, 0, stream>>>(encb, attn, spart);
        context_reduce_kernel<<<(B_ * E_) / 256, 256, 0, stream>>>(spart, ctx);
    } else {
        float* scores = spart;
        hipMemsetAsync(scores, 0, (size_t)M_ * sizeof(float), stream);
        hipMemsetAsync(ctx, 0, (size_t)B_ * E_ * sizeof(float), stream);
        dec_proj_wave_kernel<<<(B_ * D_) / 4, 256, 0, stream>>>(hidden, Wd, dec);
        dim3 g2(M_ / BM, D_ / BN);
        score_gemm_kernel<<<g2, 256, 0, stream>>>(enc, We, dec, v, scores);
        softmax_kernel<<<B_, 256, 0, stream>>>(scores, attn);
        context_kernel<<<B_ * 4 * 8, 256, 0, stream>>>(enc, attn, ctx);
    }
}

// Round 4
// 529.034 us; speedup vs baseline: 1.0649x; 1.0187x over previous
//
#include <hip/hip_runtime.h>
#include <cmath>
#include <cstdint>

// Problem constants: B=32, S=2048, E=1024, D=1024
constexpr int B_ = 32;
constexpr int S_ = 2048;
constexpr int E_ = 1024;
constexpr int D_ = 1024;
constexpr int K_ = E_;        // GEMM K
constexpr int M_ = S_ * B_;   // 65536 rows (m = s*B + b)
constexpr int SC_ = 32;       // context s-chunks
constexpr int NP_ = 16;       // score partial planes (4 nb x 4 wn)

typedef float f32x4 __attribute__((ext_vector_type(4)));
typedef float fvec4 __attribute__((ext_vector_type(4)));
typedef __bf16 bf16x8 __attribute__((ext_vector_type(8)));
typedef __attribute__((address_space(3))) uint32_t lds_u32;
typedef const __attribute__((address_space(1))) uint32_t g_u32;

// fast tanh: 1 - 2/(exp(2x)+1); saturates correctly; ~6 VALU ops
__device__ __forceinline__ float fast_tanh(float x) {
    float e = __builtin_amdgcn_exp2f(x * 2.88539008177793f);
    return 1.f - 2.f * __builtin_amdgcn_rcpf(e + 1.f);
}

__device__ __forceinline__ uint16_t f2bf(float f) {
    uint32_t u = __float_as_uint(f);
    u += 0x7FFFu + ((u >> 16) & 1u);
    return (uint16_t)(u >> 16);
}

// ---------------------------------------------------------------------------
// K0: fused prep: fp32->bf16 convert (enc, We) + dec_proj.
// ---------------------------------------------------------------------------
constexpr int ENC_N8 = M_ * K_ / 8;   // 8388608
constexpr int WE_N8  = D_ * K_ / 8;   // 131072
constexpr int CVT_BLOCKS = (ENC_N8 + WE_N8) / 256;  // 33280
constexpr int DEC_BLOCKS = (B_ * D_) / 4;           // 8192

__global__ __launch_bounds__(256) void prep_kernel(
    const float* __restrict__ enc, uint16_t* __restrict__ encb,
    const float* __restrict__ We,  uint16_t* __restrict__ Web,
    const float* __restrict__ hidden, const float* __restrict__ Wd,
    float* __restrict__ dec)
{
    const int bid = blockIdx.x;
    if (bid < CVT_BLOCKS) {
        int tid = bid * 256 + threadIdx.x;
        const float* src;
        uint16_t* dst;
        int i8;
        if (tid < ENC_N8) { src = enc; dst = encb; i8 = tid; }
        else              { src = We;  dst = Web;  i8 = tid - ENC_N8; }
        const fvec4* s4 = reinterpret_cast<const fvec4*>(src) + (size_t)i8 * 2;
        fvec4 a = __builtin_nontemporal_load(s4);
        fvec4 b = __builtin_nontemporal_load(s4 + 1);
        uint4 o;
        o.x = (uint32_t)f2bf(a.x) | ((uint32_t)f2bf(a.y) << 16);
        o.y = (uint32_t)f2bf(a.z) | ((uint32_t)f2bf(a.w) << 16);
        o.z = (uint32_t)f2bf(b.x) | ((uint32_t)f2bf(b.y) << 16);
        o.w = (uint32_t)f2bf(b.z) | ((uint32_t)f2bf(b.w) << 16);
        reinterpret_cast<uint4*>(dst)[i8] = o;
    } else {
        const int o = (bid - CVT_BLOCKS) * 4 + (threadIdx.x >> 6);
        const int lane = threadIdx.x & 63;
        const int b = o >> 10;
        const int d = o & (D_ - 1);
        const float4* h4 = reinterpret_cast<const float4*>(hidden + (size_t)b * D_);
        const float4* w4 = reinterpret_cast<const float4*>(Wd + (size_t)d * D_);
        float acc = 0.f;
#pragma unroll
        for (int p = 0; p < 4; ++p) {
            float4 h = h4[lane + p * 64], w = w4[lane + p * 64];
            acc += h.x * w.x + h.y * w.y + h.z * w.z + h.w * w.w;
        }
#pragma unroll
        for (int off = 32; off > 0; off >>= 1) acc += __shfl_xor(acc, off);
        if (lane == 0) dec[o] = acc;
    }
}

// ---------------------------------------------------------------------------
// K2: MFMA bf16 GEMM fused with tanh + v-dot -> 16 partial score planes.
// 256x256 tile, BK=32, 8 waves (2M x 4N), 4-deep LDS ring (128 KiB),
// counted vmcnt(4) (slots t AND t+1 readable after each barrier),
// XOR-swizzled LDS staged via pre-swizzled per-lane global_load_lds sources.
// Per-wave software pipelining of LDS->reg fragment loads:
//   - a1 frags (slot t) issued before cluster-0 MFMAs, consumed by cluster-1
//   - next tile's a0/bv frags (slot t+1) issued before cluster-1 MFMAs,
//     consumed by next tile's cluster-0 (ping-pong register naming)
// No lgkmcnt(0): the compiler emits counted lgkm waits from data deps, so
// LDS service overlaps MFMA pipe execution within each wave (ILP, does not
// depend on occupancy, which is LDS-capped at 1 block/CU).
// ---------------------------------------------------------------------------
constexpr int TM2 = 256, TN2 = 256, TK2 = 32;
constexpr int NT2 = K_ / TK2;            // 32 K-tiles
constexpr int TILE_B = TM2 * TK2 * 2;    // 16384 B per matrix tile
constexpr int BUF_B  = TILE_B * 2;       // 32768 B per ring slot (A+B)

#define STAGE_A(T)                                                            \
  do { char* sb_ = ldsc + (((T) + 3) & 3) * BUF_B;                            \
    __builtin_amdgcn_global_load_lds((g_u32*)pA0, (lds_u32*)(sb_ + dst0), 16, 0, 0); \
    __builtin_amdgcn_global_load_lds((g_u32*)pA1, (lds_u32*)(sb_ + dst1), 16, 0, 0); \
    pA0 += TK2; pA1 += TK2; } while (0)

#define STAGE_B(T)                                                            \
  do { char* sb_ = ldsc + (((T) + 3) & 3) * BUF_B + TILE_B;                   \
    __builtin_amdgcn_global_load_lds((g_u32*)pB0, (lds_u32*)(sb_ + dst0), 16, 0, 0); \
    __builtin_amdgcn_global_load_lds((g_u32*)pB1, (lds_u32*)(sb_ + dst1), 16, 0, 0); \
    pB0 += TK2; pB1 += TK2; } while (0)

// One K-tile, register-pipelined. aC/bC: current c0 frags (loaded during the
// previous tile). aN/bN: preloaded here for the NEXT tile's c0.
#define TILE_PIPE(T, DO_STAGE, aC, bC, aN, bN)                                \
  do {                                                                        \
    const char* bufA_  = ldsc + ((T) & 3) * BUF_B;                            \
    const char* bufAn_ = ldsc + (((T) + 1) & 3) * BUF_B;                      \
    const char* bufBn_ = bufAn_ + TILE_B;                                     \
    bf16x8 a1_[4];                                                            \
    _Pragma("unroll")                                                         \
    for (int i = 0; i < 4; ++i)                                               \
      a1_[i] = __builtin_bit_cast(bf16x8,                                     \
          *reinterpret_cast<const int4*>(bufA_ + offA[4 + i]));               \
    if (DO_STAGE) STAGE_A(T);                                                 \
    __builtin_amdgcn_sched_barrier(0);                                        \
    __builtin_amdgcn_s_setprio(1);                                            \
    _Pragma("unroll")                                                         \
    for (int i = 0; i < 4; ++i)                                               \
      _Pragma("unroll")                                                       \
      for (int j = 0; j < 4; ++j)                                             \
        acc[i][j] = __builtin_amdgcn_mfma_f32_16x16x32_bf16(                  \
            aC[i], bC[j], acc[i][j], 0, 0, 0);                                \
    __builtin_amdgcn_s_setprio(0);                                            \
    __builtin_amdgcn_sched_barrier(0);                                        \
    _Pragma("unroll")                                                         \
    for (int i = 0; i < 4; ++i)                                               \
      aN[i] = __builtin_bit_cast(bf16x8,                                      \
          *reinterpret_cast<const int4*>(bufAn_ + offA[i]));                  \
    _Pragma("unroll")                                                         \
    for (int j = 0; j < 4; ++j)                                               \
      bN[j] = __builtin_bit_cast(bf16x8,                                      \
          *reinterpret_cast<const int4*>(bufBn_ + offB[j]));                  \
    if (DO_STAGE) STAGE_B(T);                                                 \
    __builtin_amdgcn_sched_barrier(0);                                        \
    __builtin_amdgcn_s_setprio(1);                                            \
    _Pragma("unroll")                                                         \
    for (int i = 0; i < 4; ++i)                                               \
      _Pragma("unroll")                                                       \
      for (int j = 0; j < 4; ++j)                                             \
        acc[4 + i][j] = __builtin_amdgcn_mfma_f32_16x16x32_bf16(              \
            a1_[i], bC[j], acc[4 + i][j], 0, 0, 0);                           \
    __builtin_amdgcn_s_setprio(0);                                            \
  } while (0)

// Final tile: no stage, no next-tile preload.
#define TILE_LAST(T, aC, bC)                                                  \
  do {                                                                        \
    const char* bufA_ = ldsc + ((T) & 3) * BUF_B;                             \
    bf16x8 a1_[4];                                                            \
    _Pragma("unroll")                                                         \
    for (int i = 0; i < 4; ++i)                                               \
      a1_[i] = __builtin_bit_cast(bf16x8,                                     \
          *reinterpret_cast<const int4*>(bufA_ + offA[4 + i]));               \
    __builtin_amdgcn_s_setprio(1);                                            \
    _Pragma("unroll")                                                         \
    for (int i = 0; i < 4; ++i)                                               \
      _Pragma("unroll")                                                       \
      for (int j = 0; j < 4; ++j)                                             \
        acc[i][j] = __builtin_amdgcn_mfma_f32_16x16x32_bf16(                  \
            aC[i], bC[j], acc[i][j], 0, 0, 0);                                \
    _Pragma("unroll")                                                         \
    for (int i = 0; i < 4; ++i)                                               \
      _Pragma("unroll")                                                       \
      for (int j = 0; j < 4; ++j)                                             \
        acc[4 + i][j] = __builtin_amdgcn_mfma_f32_16x16x32_bf16(              \
            a1_[i], bC[j], acc[4 + i][j], 0, 0, 0);                           \
    __builtin_amdgcn_s_setprio(0);                                            \
  } while (0)

#define SYNC_VM4() do { asm volatile("s_waitcnt vmcnt(4)" ::: "memory");      \
                        __builtin_amdgcn_s_barrier(); } while (0)
#define SYNC_VM0() do { asm volatile("s_waitcnt vmcnt(0)" ::: "memory");      \
                        __builtin_amdgcn_s_barrier(); } while (0)

__global__ __launch_bounds__(512, 2) void score_mfma_kernel(
    const uint16_t* __restrict__ A,   // enc bf16 [M, K]
    const uint16_t* __restrict__ Bw,  // We  bf16 [D, K]
    const float* __restrict__ dec,    // [B, D]
    const float* __restrict__ v,      // [D]
    float* __restrict__ spart)        // [NP_, M_]  (rows are b*S + s)
{
    __shared__ __align__(16) uint16_t smem[4 * 2 * TM2 * TK2];  // 128 KiB

    // XCD-aware decode: the 4 n-blocks of one m-tile sit on one XCD
    const int p    = blockIdx.x;
    const int xcd  = p & 7;
    const int slot = p >> 3;
    const int nb   = slot & 3;
    const int mb   = xcd + 8 * (slot >> 2);
    const int m0 = mb * TM2;
    const int n0 = nb * TN2;

    const int tid  = threadIdx.x;
    const int wave = tid >> 6;        // 0..7
    const int lane = tid & 63;
    const int wm   = wave >> 2;       // 0..1 : 128 output rows each
    const int wn   = wave & 3;        // 0..3 : 64 output cols each
    const int q    = lane >> 4;
    const int r16  = lane & 15;

    char* ldsc = (char*)smem;

    // ds_read byte offsets within one 16 KiB matrix tile (swizzled).
    // element (row,k) stored at (row*64 + k*2) ^ ((row&7)<<4)
    int offA[8], offB[4];
#pragma unroll
    for (int i = 0; i < 8; ++i) {
        const int r = wm * 128 + i * 16 + r16;
        offA[i] = (r * 64 + q * 16) ^ ((r & 7) << 4);
    }
#pragma unroll
    for (int j = 0; j < 4; ++j) {
        const int r = wn * 64 + j * 16 + r16;
        offB[j] = (r * 64 + q * 16) ^ ((r & 7) << 4);
    }

    // staging sources: global_load_lds writes LDS linearly (base+lane*16),
    // so the swizzle is applied by permuting the per-lane GLOBAL source.
    // stored row rS = chunk + (lane>>2); logical row = rS ^ ((rS>>2)&1);
    // logical k-granule = (lane&3) ^ (rowL&3).
    const int l2     = lane >> 2;
    const int bbit   = (lane >> 4) & 1;
    const int rowSwz = l2 ^ bbit;                   // 0..15
    const int gsel   = (lane & 3) ^ (rowSwz & 3);   // 0..3
    const uint16_t* pA0 = A  + (size_t)(m0 + wave * 32 +  0 + rowSwz) * K_ + gsel * 8;
    const uint16_t* pA1 = A  + (size_t)(m0 + wave * 32 + 16 + rowSwz) * K_ + gsel * 8;
    const uint16_t* pB0 = Bw + (size_t)(n0 + wave * 32 +  0 + rowSwz) * K_ + gsel * 8;
    const uint16_t* pB1 = Bw + (size_t)(n0 + wave * 32 + 16 + rowSwz) * K_ + gsel * 8;
    const int dst0 = wave * 2048;      // this wave's first 1 KiB within a tile
    const int dst1 = dst0 + 1024;

    // prologue: stage tiles 0,1,2 (ring slots 0,1,2); FIFO [t0 x4][t1 x4][t2 x4]
#pragma unroll
    for (int tt = 0; tt < 3; ++tt) {
        char* sb = ldsc + tt * BUF_B;
        __builtin_amdgcn_global_load_lds((g_u32*)pA0, (lds_u32*)(sb + dst0), 16, 0, 0);
        __builtin_amdgcn_global_load_lds((g_u32*)pA1, (lds_u32*)(sb + dst1), 16, 0, 0);
        __builtin_amdgcn_global_load_lds((g_u32*)pB0, (lds_u32*)(sb + TILE_B + dst0), 16, 0, 0);
        __builtin_amdgcn_global_load_lds((g_u32*)pB1, (lds_u32*)(sb + TILE_B + dst1), 16, 0, 0);
        pA0 += TK2; pA1 += TK2; pB0 += TK2; pB1 += TK2;
    }
    // tiles 0 AND 1 landed (leaves [t2:4] in flight)
    asm volatile("s_waitcnt vmcnt(4)" ::: "memory");
    __builtin_amdgcn_s_barrier();

    f32x4 acc[8][4] = {};

    // preload c0 fragments of tile 0 (slot 0)
    bf16x8 aA[4], bA[4], aB[4], bB[4];
#pragma unroll
    for (int i = 0; i < 4; ++i)
        aA[i] = __builtin_bit_cast(bf16x8,
            *reinterpret_cast<const int4*>(ldsc + offA[i]));
#pragma unroll
    for (int j = 0; j < 4; ++j)
        bA[j] = __builtin_bit_cast(bf16x8,
            *reinterpret_cast<const int4*>(ldsc + TILE_B + offB[j]));

    // main loop: tiles 0..27 (all staging). Per-wave VMEM FIFO at tile end =
    // [t+2:4][t+3:4]; vmcnt(4) retires t+2's loads -> slots t+1, t+2 readable
    // after the barrier (t+2's loads had >=1 full tile in flight).
#pragma unroll 2
    for (int tp = 0; tp < 14; ++tp) {
        const int t = tp * 2;
        TILE_PIPE(t,     true, aA, bA, aB, bB);
        SYNC_VM4();
        TILE_PIPE(t + 1, true, aB, bB, aA, bA);
        SYNC_VM4();
    }
    TILE_PIPE(28, true,  aA, bA, aB, bB);   // stages tile 31
    SYNC_VM4();
    TILE_PIPE(29, false, aB, bB, aA, bA);
    SYNC_VM0();                             // tile 31 landed
    TILE_PIPE(30, false, aA, bA, aB, bB);
    __builtin_amdgcn_s_barrier();
    TILE_LAST(31, aB, bB);

    // epilogue: C/D layout col = lane&15, row = q*4 + reg.
    // dec/v loaded here (not preloaded) to keep main-loop VGPRs down.
    float vj[4];
#pragma unroll
    for (int j = 0; j < 4; ++j) vj[j] = v[n0 + wn * 64 + j * 16 + r16];
    float dec_r[2][4][4];   // [i&1][r][j]; b = (i&1)*16 + q*4 + r
#pragma unroll
    for (int i01 = 0; i01 < 2; ++i01)
#pragma unroll
        for (int r = 0; r < 4; ++r) {
            const int b = i01 * 16 + q * 4 + r;
#pragma unroll
            for (int j = 0; j < 4; ++j)
                dec_r[i01][r][j] = dec[b * D_ + n0 + wn * 64 + j * 16 + r16];
        }

    float* plane = spart + (size_t)(nb * 4 + wn) * M_;

#pragma unroll
    for (int i = 0; i < 8; ++i) {
#pragma unroll
        for (int r = 0; r < 4; ++r) {
            const int m = m0 + wm * 128 + i * 16 + q * 4 + r;
            const int b = (i & 1) * 16 + q * 4 + r;
            float pv = 0.f;
#pragma unroll
            for (int j = 0; j < 4; ++j)
                pv += vj[j] * fast_tanh(acc[i][j][r] + dec_r[i & 1][r][j]);
            pv += __shfl_xor(pv, 1);
            pv += __shfl_xor(pv, 2);
            pv += __shfl_xor(pv, 4);
            pv += __shfl_xor(pv, 8);
            if (r16 == 0) plane[b * S_ + (m >> 5)] = pv;
        }
    }
}

// ---------------------------------------------------------------------------
// K3: softmax over s per batch; sums the 16 partial planes first.
// ---------------------------------------------------------------------------
__global__ __launch_bounds__(256) void softmax16_kernel(
    const float* __restrict__ spart,  // [NP_, M_], plane rows are [b][s]
    float* __restrict__ attn)         // [B, S]
{
    const int b = blockIdx.x;
    const int t = threadIdx.x;
    __shared__ float sm[256];

    const float4* base = reinterpret_cast<const float4*>(spart + (size_t)b * S_);
    constexpr int PSTRIDE = M_ / 4;
    float4 v0 = {0, 0, 0, 0}, v1 = {0, 0, 0, 0};
#pragma unroll
    for (int p = 0; p < NP_; ++p) {
        float4 a = base[(size_t)p * PSTRIDE + t];
        float4 c = base[(size_t)p * PSTRIDE + t + 256];
        v0.x += a.x; v0.y += a.y; v0.z += a.z; v0.w += a.w;
        v1.x += c.x; v1.y += c.y; v1.z += c.z; v1.w += c.w;
    }

    float lmax = fmaxf(fmaxf(fmaxf(v0.x, v0.y), fmaxf(v0.z, v0.w)),
                       fmaxf(fmaxf(v1.x, v1.y), fmaxf(v1.z, v1.w)));
    sm[t] = lmax; __syncthreads();
    for (int off = 128; off > 0; off >>= 1) {
        if (t < off) sm[t] = fmaxf(sm[t], sm[t + off]);
        __syncthreads();
    }
    const float mx = sm[0];
    __syncthreads();

    v0.x = __builtin_amdgcn_exp2f((v0.x - mx) * 1.44269504f);
    v0.y = __builtin_amdgcn_exp2f((v0.y - mx) * 1.44269504f);
    v0.z = __builtin_amdgcn_exp2f((v0.z - mx) * 1.44269504f);
    v0.w = __builtin_amdgcn_exp2f((v0.w - mx) * 1.44269504f);
    v1.x = __builtin_amdgcn_exp2f((v1.x - mx) * 1.44269504f);
    v1.y = __builtin_amdgcn_exp2f((v1.y - mx) * 1.44269504f);
    v1.z = __builtin_amdgcn_exp2f((v1.z - mx) * 1.44269504f);
    v1.w = __builtin_amdgcn_exp2f((v1.w - mx) * 1.44269504f);

    float lsum = v0.x + v0.y + v0.z + v0.w + v1.x + v1.y + v1.z + v1.w;
    sm[t] = lsum; __syncthreads();
    for (int off = 128; off > 0; off >>= 1) {
        if (t < off) sm[t] += sm[t + off];
        __syncthreads();
    }
    const float inv = 1.f / sm[0];
    float4* op = reinterpret_cast<float4*>(attn + (size_t)b * S_);
    v0.x *= inv; v0.y *= inv; v0.z *= inv; v0.w *= inv;
    v1.x *= inv; v1.y *= inv; v1.z *= inv; v1.w *= inv;
    op[t] = v0; op[t + 256] = v1;
}

// ---------------------------------------------------------------------------
// K4a: context partials (reuses spart region); K4b: reduce.
// ---------------------------------------------------------------------------
__global__ __launch_bounds__(256) void context_part_kernel(
    const uint16_t* __restrict__ encb, const float* __restrict__ attn,
    float* __restrict__ part)          // [SC_, B, E]
{
    const int b  = blockIdx.x & (B_ - 1);
    const int sc = blockIdx.x >> 5;
    const int e0 = threadIdx.x * 4;
    constexpr int SLEN = S_ / SC_;     // 64

    float a0 = 0.f, a1 = 0.f, a2 = 0.f, a3 = 0.f;
    const int s0 = sc * SLEN;
#pragma unroll 2
    for (int s = s0; s < s0 + SLEN; ++s) {
        const float w = attn[b * S_ + s];
        uint2 u = *reinterpret_cast<const uint2*>(
            encb + ((size_t)s * B_ + b) * E_ + e0);
        a0 += w * __uint_as_float((u.x & 0xFFFFu) << 16);
        a1 += w * __uint_as_float(u.x & 0xFFFF0000u);
        a2 += w * __uint_as_float((u.y & 0xFFFFu) << 16);
        a3 += w * __uint_as_float(u.y & 0xFFFF0000u);
    }
    float4 o = {a0, a1, a2, a3};
    *reinterpret_cast<float4*>(part + ((size_t)sc * B_ + b) * E_ + e0) = o;
}

__global__ __launch_bounds__(256) void context_reduce_kernel(
    const float* __restrict__ part, float* __restrict__ ctx)
{
    const int i = blockIdx.x * 256 + threadIdx.x;
    float acc = 0.f;
#pragma unroll
    for (int sc = 0; sc < SC_; ++sc) acc += part[(size_t)sc * B_ * E_ + i];
    ctx[i] = acc;
}

// ---------------------------------------------------------------------------
// Fallback fp32 path (ws too small)
// ---------------------------------------------------------------------------
constexpr int BM = 64, BN = 64, BK = 16;

__global__ __launch_bounds__(256) void dec_proj_wave_kernel(
    const float* __restrict__ hidden, const float* __restrict__ Wd,
    float* __restrict__ dec)
{
    const int o = blockIdx.x * 4 + (threadIdx.x >> 6);
    const int lane = threadIdx.x & 63;
    const int b = o >> 10;
    const int d = o & (D_ - 1);
    const float4* h4 = reinterpret_cast<const float4*>(hidden + (size_t)b * D_);
    const float4* w4 = reinterpret_cast<const float4*>(Wd + (size_t)d * D_);
    float acc = 0.f;
#pragma unroll
    for (int p = 0; p < 4; ++p) {
        float4 h = h4[lane + p * 64], w = w4[lane + p * 64];
        acc += h.x * w.x + h.y * w.y + h.z * w.z + h.w * w.w;
    }
#pragma unroll
    for (int off = 32; off > 0; off >>= 1) acc += __shfl_xor(acc, off);
    if (lane == 0) dec[o] = acc;
}

__global__ __launch_bounds__(256) void score_gemm_kernel(
    const float* __restrict__ enc, const float* __restrict__ We,
    const float* __restrict__ dec, const float* __restrict__ v,
    float* __restrict__ scores)
{
    __shared__ float As[BM][BK + 1];
    __shared__ float Bs[BN][BK + 1];
    __shared__ float red[BM][17];
    const int m0 = blockIdx.x * BM;
    const int n0 = blockIdx.y * BN;
    const int t  = threadIdx.x;
    const int tx = t & 15;
    const int ty = t >> 4;
    const int lrow = t >> 2;
    const int lcol = (t & 3) * 4;
    float acc[4][4] = {};
    for (int k0 = 0; k0 < E_; k0 += BK) {
        float4 a = *reinterpret_cast<const float4*>(enc + (size_t)(m0 + lrow) * E_ + k0 + lcol);
        float4 w = *reinterpret_cast<const float4*>(We + (size_t)(n0 + lrow) * E_ + k0 + lcol);
        As[lrow][lcol + 0] = a.x; As[lrow][lcol + 1] = a.y;
        As[lrow][lcol + 2] = a.z; As[lrow][lcol + 3] = a.w;
        Bs[lrow][lcol + 0] = w.x; Bs[lrow][lcol + 1] = w.y;
        Bs[lrow][lcol + 2] = w.z; Bs[lrow][lcol + 3] = w.w;
        __syncthreads();
#pragma unroll
        for (int kk = 0; kk < BK; ++kk) {
            float av[4], bw[4];
#pragma unroll
            for (int i = 0; i < 4; ++i) av[i] = As[ty * 4 + i][kk];
#pragma unroll
            for (int j = 0; j < 4; ++j) bw[j] = Bs[tx * 4 + j][kk];
#pragma unroll
            for (int i = 0; i < 4; ++i)
#pragma unroll
                for (int j = 0; j < 4; ++j)
                    acc[i][j] += av[i] * bw[j];
        }
        __syncthreads();
    }
    float pp[4];
#pragma unroll
    for (int i = 0; i < 4; ++i) {
        int m = m0 + ty * 4 + i;
        int b = m & (B_ - 1);
        float s = 0.f;
#pragma unroll
        for (int j = 0; j < 4; ++j) {
            int n = n0 + tx * 4 + j;
            s += v[n] * tanhf(acc[i][j] + dec[b * D_ + n]);
        }
        pp[i] = s;
    }
#pragma unroll
    for (int i = 0; i < 4; ++i) red[ty * 4 + i][tx] = pp[i];
    __syncthreads();
    if (t < BM) {
        float s = 0.f;
#pragma unroll
        for (int j = 0; j < 16; ++j) s += red[t][j];
        atomicAdd(&scores[m0 + t], s);
    }
}

__global__ __launch_bounds__(256) void softmax_kernel(
    const float* __restrict__ scores, float* __restrict__ attn)
{
    const int b = blockIdx.x;
    const int t = threadIdx.x;
    __shared__ float sm[256];
    float vals[8];
    float lmax = -INFINITY;
#pragma unroll
    for (int i = 0; i < 8; ++i) {
        int s = t + i * 256;
        vals[i] = scores[s * B_ + b];
        lmax = fmaxf(lmax, vals[i]);
    }
    sm[t] = lmax; __syncthreads();
    for (int off = 128; off > 0; off >>= 1) {
        if (t < off) sm[t] = fmaxf(sm[t], sm[t + off]);
        __syncthreads();
    }
    const float mx = sm[0];
    __syncthreads();
    float lsum = 0.f;
#pragma unroll
    for (int i = 0; i < 8; ++i) {
        vals[i] = expf(vals[i] - mx);
        lsum += vals[i];
    }
    sm[t] = lsum; __syncthreads();
    for (int off = 128; off > 0; off >>= 1) {
        if (t < off) sm[t] += sm[t + off];
        __syncthreads();
    }
    const float inv = 1.f / sm[0];
#pragma unroll
    for (int i = 0; i < 8; ++i)
        attn[b * S_ + t + i * 256] = vals[i] * inv;
}

__global__ __launch_bounds__(256) void context_kernel(
    const float* __restrict__ enc, const float* __restrict__ attn,
    float* __restrict__ ctx)
{
    const int e0 = (blockIdx.x & 3) * 256;
    const int b  = (blockIdx.x >> 2) & (B_ - 1);
    const int sc = blockIdx.x >> 7;
    const int e  = e0 + threadIdx.x;
    float acc = 0.f;
    const int s_end = sc * 256 + 256;
    for (int s = sc * 256; s < s_end; ++s)
        acc += attn[b * S_ + s] * enc[((size_t)s * B_ + b) * E_ + e];
    atomicAdd(&ctx[b * E_ + e], acc);
}

// ---------------------------------------------------------------------------
extern "C" void kernel_launch(void* const* d_in, const int* in_sizes, int n_in,
                              void* d_out, int out_size, void* d_ws, size_t ws_size,
                              hipStream_t stream) {
    const float* hidden = (const float*)d_in[0];
    const float* enc    = (const float*)d_in[1];
    const float* We     = (const float*)d_in[2];
    const float* Wd     = (const float*)d_in[3];
    const float* v      = (const float*)d_in[4];

    float* ctx  = (float*)d_out;
    float* attn = (float*)d_out + B_ * E_;

    float*    dec   = (float*)d_ws;                  // [B*D]
    float*    spart = dec + B_ * D_;                 // [NP_*M_] (reused as ctx partials)
    uint16_t* Web   = (uint16_t*)(spart + (size_t)NP_ * M_);  // [D*K]
    uint16_t* encb  = Web + (size_t)D_ * K_;         // [M*K]

    const size_t need = (size_t)B_ * D_ * 4 + (size_t)NP_ * M_ * 4
                      + ((size_t)D_ * K_ + (size_t)M_ * K_) * 2;
    const bool fast = ws_size >= need;

    if (fast) {
        prep_kernel<<<CVT_BLOCKS + DEC_BLOCKS, 256, 0, stream>>>(
            enc, encb, We, Web, hidden, Wd, dec);

        score_mfma_kernel<<<(M_ / TM2) * (D_ / TN2), 512, 0, stream>>>(
            encb, Web, dec, v, spart);

        softmax16_kernel<<<B_, 256, 0, stream>>>(spart, attn);
        context_part_kernel<<<SC_ * B_, 256, 0, stream>>>(encb, attn, spart);
        context_reduce_kernel<<<(B_ * E_) / 256, 256, 0, stream>>>(spart, ctx);
    } else {
        float* scores = spart;
        hipMemsetAsync(scores, 0, (size_t)M_ * sizeof(float), stream);
        hipMemsetAsync(ctx, 0, (size_t)B_ * E_ * sizeof(float), stream);
        dec_proj_wave_kernel<<<(B_ * D_) / 4, 256, 0, stream>>>(hidden, Wd, dec);
        dim3 g2(M_ / BM, D_ / BN);
        score_gemm_kernel<<<g2, 256, 0, stream>>>(enc, We, dec, v, scores);
        softmax_kernel<<<B_, 256, 0, stream>>>(scores, attn);
        context_kernel<<<B_ * 4 * 8, 256, 0, stream>>>(enc, attn, ctx);
    }
}